// Round 5
// baseline (1391.769 us; speedup 1.0000x reference)
//
#include <hip/hip_runtime.h>
#include <hip/hip_bf16.h>
#include <math.h>

typedef __hip_bfloat16 bf16;
typedef unsigned short ushort;
typedef __attribute__((ext_vector_type(8))) short s16x8;   // 8 bf16 (4 VGPRs)
typedef __attribute__((ext_vector_type(4))) float f32x4;

__device__ __forceinline__ float b2f(bf16 v){ return __bfloat162float(v); }
__device__ __forceinline__ bf16  f2b(float v){ return __float2bfloat16(v); }
__device__ __forceinline__ ushort f2u(float v){
    union { bf16 b; ushort u; } cv; cv.b = __float2bfloat16(v); return cv.u;
}

// residual row address in the split d_out layout:
// token t in concat space (w = t/65, r = t%65): r<16 -> out_ct slot (w*16+r),
// else out_x row (w*49 + r-16). split==0: contiguous ct rows (carrier path).
__device__ __forceinline__ float* row_addr(float* ct, float* x, int t, int split)
{
    if (!split) return ct + (size_t)t * 128;
    int w = t / 65, r = t - w * 65;
    if (r < 16) return ct + ((size_t)w * 16 + r) * 128;
    return x + ((size_t)w * 49 + (r - 16)) * 128;
}

// ---------------- posemb MLP: out[seq][128] = relu(t@w1+b1)@w2 (fp32) ----------------
__global__ void posemb_kernel(const float* __restrict__ w1, const float* __restrict__ b1,
                              const float* __restrict__ w2, float* __restrict__ out, int s)
{
    int i = blockIdx.x;
    int c = threadIdx.x;
    int half = s / 2;
    float t0 = (float)(i / s - half) / (float)half;
    float t1 = (float)(i % s - half) / (float)half;
    float acc = 0.f;
    for (int k = 0; k < 512; k++){
        float h = t0 * w1[k] + t1 * w1[512 + k] + b1[k];
        h = fmaxf(h, 0.f);
        acc += h * w2[k * 128 + c];
    }
    out[i * 128 + c] = acc;
}

// ------------- CPB table: tbl[(2ws-1)^2][4] = 16*sigmoid(relu(t@w1+b1)@w2) -------------
__global__ void cpb_kernel(const float* __restrict__ w1, const float* __restrict__ b1,
                           const float* __restrict__ w2, float* __restrict__ tbl, int ws)
{
    int d = 2 * ws - 1;
    int ne = d * d;
    int e = blockIdx.x * 64 + threadIdx.x;
    if (e >= ne) return;
    float rh = (float)(e / d - (ws - 1));
    float rw = (float)(e % d - (ws - 1));
    float t0 = rh / (float)(ws - 1) * 8.f;
    float t1 = rw / (float)(ws - 1) * 8.f;
    float s0 = (t0 > 0.f) ? 1.f : ((t0 < 0.f) ? -1.f : 0.f);
    float s1 = (t1 > 0.f) ? 1.f : ((t1 < 0.f) ? -1.f : 0.f);
    t0 = s0 * log2f(fabsf(t0) + 1.f) * (1.f / 3.f);
    t1 = s1 * log2f(fabsf(t1) + 1.f) * (1.f / 3.f);
    float acc[4] = {0.f, 0.f, 0.f, 0.f};
    for (int k = 0; k < 512; k++){
        float h = t0 * w1[k] + t1 * w1[512 + k] + b1[k];
        h = fmaxf(h, 0.f);
        #pragma unroll
        for (int hh = 0; hh < 4; hh++) acc[hh] += h * w2[k * 4 + hh];
    }
    #pragma unroll
    for (int hh = 0; hh < 4; hh++)
        tbl[e * 4 + hh] = 16.f / (1.f + expf(-acc[hh]));
}

// ---------------- ct_init: out_ct = ct + hpe ----------------
__global__ void ct_init_kernel(const float* __restrict__ ct, const float* __restrict__ hpe,
                               float* __restrict__ out_ct)
{
    int idx = blockIdx.x * 256 + threadIdx.x;      // over 65536*128
    out_ct[idx] = ct[idx] + hpe[idx % (256 * 128)];
}

// ---------------- pack W[K][N] (fp32) into MFMA B-frag order (bf16) ----------------
// out[((nt*KT + kt)*64 + lane)*8 + j] = bf16(W[(kt*32 + (lane>>4)*8 + j)*N + nt*16 + (lane&15)])
__global__ void pack_w_kernel(const float* __restrict__ W, ushort* __restrict__ out,
                              int N, int KT)
{
    int idx = blockIdx.x * 256 + threadIdx.x;
    int j   = idx & 7;
    int l   = (idx >> 3) & 63;
    int rest= idx >> 9;
    int kt  = rest % KT;
    int nt  = rest / KT;
    int k   = kt * 32 + ((l >> 4) << 3) + j;
    int c   = nt * 16 + (l & 15);
    out[idx] = f2u(W[(size_t)k * N + c]);
}

#define SWZ(r,c)  ((r)*128 + ((c) ^ (((r)&7)<<3)))
#define SWZ5(r,c) ((r)*512 + ((c) ^ (((r)&7)<<3)))

// ---------------- carrier fused LN + QKV GEMM (MFMA), bf16 out ----------------
// 32 tokens/block, 4 waves; wave owns 6 of 24 N-tiles x both 16-row strips.
__global__ __launch_bounds__(256) void qkv_mfma(
    const float* __restrict__ ct_res,
    const float* __restrict__ g, const float* __restrict__ b,
    const ushort* __restrict__ Wpk,       // [24][4][64][8]
    ushort* __restrict__ qkvB)            // [65536][384] bf16
{
    __shared__ ushort Xs[32*128];
    int m0b = blockIdx.x * 32;
    int tid = threadIdx.x;
    int wv  = tid >> 6, lane = tid & 63;
    int q   = lane >> 4, c15 = lane & 15;

    for (int t = wv; t < 32; t += 4){
        const float* row = ct_res + (size_t)(m0b + t) * 128;
        float v0 = row[lane], v1 = row[lane + 64];
        float s = v0 + v1, s2 = v0 * v0 + v1 * v1;
        #pragma unroll
        for (int off = 32; off >= 1; off >>= 1){
            s  += __shfl_xor(s,  off, 64);
            s2 += __shfl_xor(s2, off, 64);
        }
        float mean = s * (1.f / 128.f);
        float var  = s2 * (1.f / 128.f) - mean * mean;
        float r = rsqrtf(var + 1e-5f);
        Xs[SWZ(t, lane)]      = f2u((v0 - mean) * r * g[lane]      + b[lane]);
        Xs[SWZ(t, lane + 64)] = f2u((v1 - mean) * r * g[lane + 64] + b[lane + 64]);
    }
    __syncthreads();

    s16x8 a1[2][4];
    #pragma unroll
    for (int mt = 0; mt < 2; mt++)
        #pragma unroll
        for (int kt = 0; kt < 4; kt++)
            a1[mt][kt] = *(const s16x8*)(Xs + SWZ(mt * 16 + c15, kt * 32 + q * 8));

    #pragma unroll
    for (int nt0 = 0; nt0 < 6; nt0++){
        int nt = wv * 6 + nt0;
        f32x4 acc0 = {0.f,0.f,0.f,0.f}, acc1 = {0.f,0.f,0.f,0.f};
        #pragma unroll
        for (int kt = 0; kt < 4; kt++){
            s16x8 bfr = *(const s16x8*)(Wpk + (((nt << 2) + kt) * 64 + lane) * 8);
            acc0 = __builtin_amdgcn_mfma_f32_16x16x32_bf16(a1[0][kt], bfr, acc0, 0, 0, 0);
            acc1 = __builtin_amdgcn_mfma_f32_16x16x32_bf16(a1[1][kt], bfr, acc1, 0, 0, 0);
        }
        #pragma unroll
        for (int r = 0; r < 4; r++){
            qkvB[(size_t)(m0b +      4 * q + r) * 384 + nt * 16 + c15] = f2u(acc0[r]);
            qkvB[(size_t)(m0b + 16 + 4 * q + r) * 384 + nt * 16 + c15] = f2u(acc1[r]);
        }
    }
}

// ---------------- carrier attention via MFMA: one block per (b, head) ----------------
// 4 waves x 4 strips of 16 rows = 256 query rows; K/V staged once per block.
__global__ __launch_bounds__(256) void carrier_attn_mfma(
    const ushort* __restrict__ qkvB,      // [65536][384] bf16
    const float* __restrict__ btbl,       // [961][4]
    float* __restrict__ out)              // [65536][128] float (attn out)
{
    __shared__ ushort Kh[256 * 40];       // [key][d32]   stride 40
    __shared__ ushort Vt[32 * 264];       // [d32][key]   stride 264
    __shared__ ushort Pb[4][16 * 264];    // per-wave [row16][key] stride 264
    __shared__ float  tbl[961];

    int bx = blockIdx.x;
    int b  = bx >> 2, h = bx & 3;
    int tid = threadIdx.x;
    int wv  = tid >> 6, lane = tid & 63;
    int q   = lane >> 4, c15 = lane & 15;
    const float scale = 0.17677669529663688f;   // 1/sqrt(32)

    // stage K (row-major) and V (transposed) for this (b,h)
    for (int idx = tid; idx < 256 * 8; idx += 256){
        int tok = idx >> 3, seg = idx & 7;
        size_t base = (size_t)(b * 256 + tok) * 384 + h * 32 + seg * 4;
        uint2 kk = *(const uint2*)(qkvB + base + 128);
        uint2 vv = *(const uint2*)(qkvB + base + 256);
        *(uint2*)(Kh + tok * 40 + seg * 4) = kk;
        ushort* vp = (ushort*)&vv;
        #pragma unroll
        for (int k2 = 0; k2 < 4; k2++) Vt[(seg * 4 + k2) * 264 + tok] = vp[k2];
    }
    for (int i = tid; i < 961; i += 256) tbl[i] = btbl[i * 4 + h];
    __syncthreads();

    ushort* Pw = Pb[wv];
    for (int s = 0; s < 4; s++){
        int st = wv * 4 + s, r0 = st * 16;
        s16x8 a = *(const s16x8*)(qkvB + (size_t)(b * 256 + r0 + c15) * 384 + h * 32 + q * 8);
        f32x4 sc[16];
        #pragma unroll
        for (int nt = 0; nt < 16; nt++){
            s16x8 bfr = *(const s16x8*)(Kh + (nt * 16 + c15) * 40 + q * 8);
            f32x4 z = {0.f,0.f,0.f,0.f};
            sc[nt] = __builtin_amdgcn_mfma_f32_16x16x32_bf16(a, bfr, z, 0, 0, 0);
        }
        float linv_r[4];
        #pragma unroll
        for (int r = 0; r < 4; r++){
            int rr = 4 * q + r;
            float sv[16];
            #pragma unroll
            for (int nt = 0; nt < 16; nt++)
                sv[nt] = sc[nt][r] * scale + tbl[(st - nt + 15) * 31 + (rr - c15 + 15)];
            float m = sv[0];
            #pragma unroll
            for (int nt = 1; nt < 16; nt++) m = fmaxf(m, sv[nt]);
            #pragma unroll
            for (int off = 8; off >= 1; off >>= 1) m = fmaxf(m, __shfl_xor(m, off, 64));
            float l = 0.f;
            #pragma unroll
            for (int nt = 0; nt < 16; nt++){
                float p = __expf(sv[nt] - m);
                sv[nt] = p; l += p;
            }
            #pragma unroll
            for (int off = 8; off >= 1; off >>= 1) l += __shfl_xor(l, off, 64);
            linv_r[r] = 1.f / l;
            #pragma unroll
            for (int nt = 0; nt < 16; nt++)
                Pw[rr * 264 + nt * 16 + c15] = f2u(sv[nt]);
        }
        // PV: O[16][32] = P[16][256] @ V[256][32]
        #pragma unroll
        for (int ntv = 0; ntv < 2; ntv++){
            f32x4 acc = {0.f,0.f,0.f,0.f};
            #pragma unroll
            for (int kt = 0; kt < 8; kt++){
                s16x8 ap = *(const s16x8*)(Pw + c15 * 264 + kt * 32 + q * 8);
                s16x8 bv = *(const s16x8*)(Vt + (ntv * 16 + c15) * 264 + kt * 32 + q * 8);
                acc = __builtin_amdgcn_mfma_f32_16x16x32_bf16(ap, bv, acc, 0, 0, 0);
            }
            #pragma unroll
            for (int r = 0; r < 4; r++)
                out[(size_t)(b * 256 + r0 + 4 * q + r) * 128 + h * 32 + ntv * 16 + c15]
                    = acc[r] * linv_r[r];
        }
    }
}

// ------------- residual GEMM (MFMA): res += gamma*(src@W + bias), K=N=128 -------------
__global__ __launch_bounds__(256) void res_gemm_mfma(
    const float* __restrict__ src, float* ct_res, float* x_res, int split,
    const ushort* __restrict__ Wpk,       // [8][4][64][8]
    const float* __restrict__ bias, const float* __restrict__ gamma)
{
    __shared__ ushort Xs[32*128];
    int m0b = blockIdx.x * 32;
    int tid = threadIdx.x;
    int wv  = tid >> 6, lane = tid & 63;
    int q   = lane >> 4, c15 = lane & 15;

    for (int t = wv; t < 32; t += 4){
        const float* row = src + (size_t)(m0b + t) * 128;
        Xs[SWZ(t, lane)]      = f2u(row[lane]);
        Xs[SWZ(t, lane + 64)] = f2u(row[lane + 64]);
    }
    __syncthreads();

    s16x8 a1[2][4];
    #pragma unroll
    for (int mt = 0; mt < 2; mt++)
        #pragma unroll
        for (int kt = 0; kt < 4; kt++)
            a1[mt][kt] = *(const s16x8*)(Xs + SWZ(mt * 16 + c15, kt * 32 + q * 8));

    f32x4 acc[2][2];
    #pragma unroll
    for (int mt = 0; mt < 2; mt++)
        #pragma unroll
        for (int p = 0; p < 2; p++) acc[mt][p] = (f32x4){0.f,0.f,0.f,0.f};

    #pragma unroll
    for (int kt = 0; kt < 4; kt++)
        #pragma unroll
        for (int p = 0; p < 2; p++){
            int nt = wv * 2 + p;
            s16x8 bfr = *(const s16x8*)(Wpk + (((nt << 2) + kt) * 64 + lane) * 8);
            acc[0][p] = __builtin_amdgcn_mfma_f32_16x16x32_bf16(a1[0][kt], bfr, acc[0][p], 0, 0, 0);
            acc[1][p] = __builtin_amdgcn_mfma_f32_16x16x32_bf16(a1[1][kt], bfr, acc[1][p], 0, 0, 0);
        }

    #pragma unroll
    for (int mt = 0; mt < 2; mt++)
        #pragma unroll
        for (int p = 0; p < 2; p++){
            int col = (wv * 2 + p) * 16 + c15;
            float gv = gamma[col], bv = bias[col];
            #pragma unroll
            for (int r = 0; r < 4; r++){
                int row = m0b + mt * 16 + 4 * q + r;
                float* pr = row_addr(ct_res, x_res, row, split) + col;
                *pr = *pr + gv * (acc[mt][p][r] + bv);
            }
        }
}

// ---------------- fused main-path window attention via MFMA ----------------
// one block per window (65 tokens padded to 80), 5 waves, one 16-row strip/wave.
// Heads processed in 2 groups of 2: one QKV phase per group (48 B-frag loads
// batched), then both heads run barrier-free (Q strip / P / O are wave-private).
// Barriers: LN, A-hoist, 2x(QKV-write, group-end) = 5 total (was 11).
__global__ __launch_bounds__(320, 2) void win_attn_mfma(
    float* ct_res, float* out_x,
    const float* __restrict__ x_in, const float* __restrict__ pe,
    const ushort* __restrict__ Wqkv_pk,  // [24][4][64][8] bf16 frags
    const float* __restrict__ g, const float* __restrict__ bta,
    const float* __restrict__ btbl,      // [169][4]
    const ushort* __restrict__ Wp_pk,    // [8][4][64][8]  bf16 frags
    const float* __restrict__ bp, const float* __restrict__ g3)
{
    __shared__ ushort sm[30976];          // 61952 B
    ushort* Qh = sm;                      // [2][80][40]
    ushort* Kh = sm + 6400;               // [2][80][40]
    ushort* Vt = sm + 12800;              // [2][32][104]
    ushort* Pb = sm + 19456;              // [80][104]  (strip-private rows)
    ushort* Ob = sm + 27776;              // [5][16][40] (wave-private)
    ushort* Xs = sm;                      // [80][128] (aliases Qh+Kh; LN phase only)

    int w   = blockIdx.x;
    int tid = threadIdx.x;
    int wv  = tid >> 6, lane = tid & 63;
    int q   = lane >> 4, c15 = lane & 15;
    int m0  = wv * 16;                       // this wave's M-strip

    // ---- LN into Xs (rows round-robin over waves); x rows read x_in + pe ----
    for (int t = wv; t < 65; t += 5){
        float v0, v1;
        if (t < 16){
            const float* row = ct_res + ((size_t)w * 16 + t) * 128;
            v0 = row[lane]; v1 = row[lane + 64];
        } else {
            const float* row = x_in + ((size_t)w * 49 + (t - 16)) * 128;
            const float* pr  = pe + (t - 16) * 128;
            v0 = row[lane] + pr[lane];
            v1 = row[lane + 64] + pr[lane + 64];
        }
        float s = v0 + v1, s2 = v0 * v0 + v1 * v1;
        #pragma unroll
        for (int off = 32; off >= 1; off >>= 1){
            s  += __shfl_xor(s,  off, 64);
            s2 += __shfl_xor(s2, off, 64);
        }
        float mean = s * (1.f / 128.f);
        float var  = s2 * (1.f / 128.f) - mean * mean;
        float rr = rsqrtf(var + 1e-5f);
        Xs[SWZ(t, lane)]      = f2u((v0 - mean) * rr * g[lane]      + bta[lane]);
        Xs[SWZ(t, lane + 64)] = f2u((v1 - mean) * rr * g[lane + 64] + bta[lane + 64]);
    }
    // zero Xs pad rows 65..79 (so strip-4 A-frags see zeros)
    for (int i = tid; i < 15 * 128; i += 320) Xs[65 * 128 + i] = 0;
    // zero pads (regions disjoint from Xs): Vt cols 80..95 both heads; Pb cols 80..95
    for (int i = tid; i < 2 * 32 * 16; i += 320){
        int hh = i >> 9, rem = i & 511;
        Vt[hh * 3328 + (rem >> 4) * 104 + 80 + (rem & 15)] = 0;
    }
    for (int i = tid; i < 80 * 16; i += 320) Pb[(i >> 4) * 104 + 80 + (i & 15)] = 0;
    __syncthreads();

    // ---- hoist this wave's QKV A-fragments into registers (Xs dies after) ----
    s16x8 a1[4];
    #pragma unroll
    for (int kt = 0; kt < 4; kt++)
        a1[kt] = *(const s16x8*)(Xs + SWZ(m0 + c15, kt * 32 + q * 8));

    // ---- precompute rel-bias indices for this lane's (row,col) pattern ----
    int  bidx[5][4];
    bool cvalid[5];
    {
        int cdiv[5], cmod[5]; bool cb[5];
        #pragma unroll
        for (int nt = 0; nt < 5; nt++){
            int col = nt * 16 + c15;
            cvalid[nt] = col < 65;
            cb[nt] = (col >= 16) && (col < 65);
            int wq = col - 16; if (wq < 0) wq = 0;
            cdiv[nt] = wq / 7; cmod[nt] = wq - cdiv[nt] * 7;
        }
        #pragma unroll
        for (int r = 0; r < 4; r++){
            int row = m0 + 4 * q + r;
            bool rb = (row >= 16) && (row < 65);
            int wp = row - 16; if (wp < 0) wp = 0;
            int rdiv = wp / 7, rmod = wp - rdiv * 7;
            #pragma unroll
            for (int nt = 0; nt < 5; nt++){
                if (rb && cb[nt]){
                    int di = rdiv - cdiv[nt] + 6;
                    int dj = rmod - cmod[nt] + 6;
                    bidx[nt][r] = (di * 13 + dj) * 4;
                } else bidx[nt][r] = -1;
            }
        }
    }
    __syncthreads();   // all a1 reads done; Qh/Kh region reusable

    f32x4 pacc[8];                           // proj accumulators (persist over heads)
    #pragma unroll
    for (int i = 0; i < 8; i++) pacc[i] = (f32x4){0.f, 0.f, 0.f, 0.f};

    ushort* Obw = Ob + wv * 640;             // wave-private [16][40]

    for (int gset = 0; gset < 2; gset++){
        // ---- QKV for heads {2g, 2g+1}: 12 col-tiles, 48 B-frag loads batched ----
        #pragma unroll
        for (int nc = 0; nc < 12; nc++){
            int mat = nc >> 2;                        // 0=q 1=k 2=v
            int hh  = (nc >> 1) & 1;                  // head within group
            int half= nc & 1;
            int h   = gset * 2 + hh;
            int ntg = mat * 8 + h * 2 + half;         // global N-tile in Wqkv
            f32x4 acc = {0.f, 0.f, 0.f, 0.f};
            #pragma unroll
            for (int kt = 0; kt < 4; kt++){
                s16x8 b = *(const s16x8*)(Wqkv_pk + (((ntg << 2) + kt) * 64 + lane) * 8);
                acc = __builtin_amdgcn_mfma_f32_16x16x32_bf16(a1[kt], b, acc, 0, 0, 0);
            }
            int colb = half * 16 + c15;               // d within head, 0..31
            #pragma unroll
            for (int r = 0; r < 4; r++){
                int row = m0 + 4 * q + r;
                ushort val = f2u(acc[r]);
                if      (mat == 0) Qh[hh * 3200 + row * 40 + colb] = val;
                else if (mat == 1) Kh[hh * 3200 + row * 40 + colb] = val;
                else               Vt[hh * 3328 + colb * 104 + row] = val;
            }
        }
        __syncthreads();

        // ---- both heads of the group: scores/softmax/PV/proj, barrier-free ----
        for (int hh = 0; hh < 2; hh++){
            int h = gset * 2 + hh;
            // scores (strip x all 5 key-tiles)
            f32x4 sc[5];
            s16x8 aq = *(const s16x8*)(Qh + hh * 3200 + (m0 + c15) * 40 + q * 8);
            #pragma unroll
            for (int nt = 0; nt < 5; nt++){
                s16x8 b = *(const s16x8*)(Kh + hh * 3200 + (nt * 16 + c15) * 40 + q * 8);
                f32x4 z = {0.f, 0.f, 0.f, 0.f};
                sc[nt] = __builtin_amdgcn_mfma_f32_16x16x32_bf16(aq, b, z, 0, 0, 0);
            }
            float linv_r[4];
            #pragma unroll
            for (int r = 0; r < 4; r++){
                float sv[5];
                #pragma unroll
                for (int nt = 0; nt < 5; nt++){
                    float x = sc[nt][r] * 0.17677669529663688f;
                    if (bidx[nt][r] >= 0) x += btbl[bidx[nt][r] + h];
                    sv[nt] = cvalid[nt] ? x : -1e30f;
                }
                float m = sv[0];
                #pragma unroll
                for (int nt = 1; nt < 5; nt++) m = fmaxf(m, sv[nt]);
                #pragma unroll
                for (int off = 8; off >= 1; off >>= 1) m = fmaxf(m, __shfl_xor(m, off, 64));
                float l = 0.f;
                #pragma unroll
                for (int nt = 0; nt < 5; nt++){
                    float p = cvalid[nt] ? __expf(sv[nt] - m) : 0.f;
                    sv[nt] = p; l += p;
                }
                #pragma unroll
                for (int off = 8; off >= 1; off >>= 1) l += __shfl_xor(l, off, 64);
                linv_r[r] = 1.f / l;
                int row = m0 + 4 * q + r;
                #pragma unroll
                for (int nt = 0; nt < 5; nt++)
                    Pb[row * 104 + nt * 16 + c15] = f2u(sv[nt]);
            }

            // PV: O[strip][32] = P[strip][96] @ V[96][32]
            #pragma unroll
            for (int ntv = 0; ntv < 2; ntv++){
                f32x4 acc = {0.f, 0.f, 0.f, 0.f};
                #pragma unroll
                for (int kt = 0; kt < 3; kt++){
                    s16x8 a = *(const s16x8*)(Pb + (m0 + c15) * 104 + kt * 32 + q * 8);
                    s16x8 b = *(const s16x8*)(Vt + hh * 3328 + (ntv * 16 + c15) * 104 + kt * 32 + q * 8);
                    acc = __builtin_amdgcn_mfma_f32_16x16x32_bf16(a, b, acc, 0, 0, 0);
                }
                #pragma unroll
                for (int r = 0; r < 4; r++)
                    Obw[(4 * q + r) * 40 + ntv * 16 + c15] = f2u(acc[r] * linv_r[r]);
            }

            // proj partial: pacc += O(strip, head h's 32ch) @ Wp[h*32:,:]
            s16x8 ao = *(const s16x8*)(Obw + c15 * 40 + q * 8);
            #pragma unroll
            for (int ntp = 0; ntp < 8; ntp++){
                s16x8 b = *(const s16x8*)(Wp_pk + (((ntp << 2) + h) * 64 + lane) * 8);
                pacc[ntp] = __builtin_amdgcn_mfma_f32_16x16x32_bf16(ao, b, pacc[ntp], 0, 0, 0);
            }
        }
        __syncthreads();   // protect Qh/Kh/Vt before next group's QKV overwrite
    }

    // ---- residual update: ct rows RMW out_ct; x rows = x_in + pe + g3*proj ----
    #pragma unroll
    for (int ntp = 0; ntp < 8; ntp++){
        int col = ntp * 16 + c15;
        float gv = g3[col], bv = bp[col];
        #pragma unroll
        for (int r = 0; r < 4; r++){
            int row = m0 + 4 * q + r;
            if (row < 65){
                float upd = gv * (pacc[ntp][r] + bv);
                if (row < 16){
                    float* pr = ct_res + ((size_t)w * 16 + row) * 128 + col;
                    *pr = *pr + upd;
                } else {
                    size_t xi = ((size_t)w * 49 + (row - 16)) * 128 + col;
                    out_x[xi] = x_in[xi] + pe[(row - 16) * 128 + col] + upd;
                }
            }
        }
    }
}

// ---------------- fused LN + MLP via MFMA (+gamma residual), 32 tokens/block ----------------
__global__ __launch_bounds__(256) void mlp_mfma(
    float* ct_res, float* x_res, int split,
    const float* __restrict__ g,  const float* __restrict__ b,
    const ushort* __restrict__ W1pk,  // [32][4][64][8]  bf16 frags (N=512,KT=4)
    const float* __restrict__ b1,
    const ushort* __restrict__ W2pk,  // [8][16][64][8]  bf16 frags (N=128,KT=16)
    const float* __restrict__ b2,
    const float* __restrict__ gamma)
{
    __shared__ ushort Xs[32*128];     // LN'd tokens, XOR-swizzled
    __shared__ ushort Hs[32*512];     // gelu hidden, XOR-swizzled

    int m0b = blockIdx.x * 32;
    int tid = threadIdx.x;
    int wv  = tid >> 6, lane = tid & 63;
    int q   = lane >> 4, c15 = lane & 15;

    // ---- LN into Xs ----
    for (int t = wv; t < 32; t += 4){
        const float* row = row_addr(ct_res, x_res, m0b + t, split);
        float v0 = row[lane], v1 = row[lane + 64];
        float s = v0 + v1, s2 = v0 * v0 + v1 * v1;
        #pragma unroll
        for (int off = 32; off >= 1; off >>= 1){
            s  += __shfl_xor(s,  off, 64);
            s2 += __shfl_xor(s2, off, 64);
        }
        float mean = s * (1.f / 128.f);
        float var  = s2 * (1.f / 128.f) - mean * mean;
        float r = rsqrtf(var + 1e-5f);
        Xs[SWZ(t, lane)]      = f2u((v0 - mean) * r * g[lane]      + b[lane]);
        Xs[SWZ(t, lane + 64)] = f2u((v1 - mean) * r * g[lane + 64] + b[lane + 64]);
    }
    __syncthreads();

    // ---- GEMM1: H = gelu(X @ W1 + b1), wave covers N-tiles [wv*8, wv*8+8) ----
    s16x8 a1[2][4];
    #pragma unroll
    for (int mt = 0; mt < 2; mt++)
        #pragma unroll
        for (int kt = 0; kt < 4; kt++)
            a1[mt][kt] = *(const s16x8*)(Xs + SWZ(mt * 16 + c15, kt * 32 + q * 8));

    #pragma unroll
    for (int nt0 = 0; nt0 < 8; nt0++){
        int nt = wv * 8 + nt0;
        f32x4 acc0 = {0.f,0.f,0.f,0.f}, acc1 = {0.f,0.f,0.f,0.f};
        #pragma unroll
        for (int kt = 0; kt < 4; kt++){
            s16x8 bfr = *(const s16x8*)(W1pk + (((nt << 2) + kt) * 64 + lane) * 8);
            acc0 = __builtin_amdgcn_mfma_f32_16x16x32_bf16(a1[0][kt], bfr, acc0, 0, 0, 0);
            acc1 = __builtin_amdgcn_mfma_f32_16x16x32_bf16(a1[1][kt], bfr, acc1, 0, 0, 0);
        }
        float bb = b1[nt * 16 + c15];
        #pragma unroll
        for (int r = 0; r < 4; r++){
            float x0 = acc0[r] + bb;
            float x1 = acc1[r] + bb;
            Hs[SWZ5(4 * q + r,      nt * 16 + c15)] =
                f2u(0.5f * x0 * (1.f + erff(x0 * 0.70710678118654752f)));
            Hs[SWZ5(16 + 4 * q + r, nt * 16 + c15)] =
                f2u(0.5f * x1 * (1.f + erff(x1 * 0.70710678118654752f)));
        }
    }
    __syncthreads();

    // ---- GEMM2: res += gamma*(H @ W2 + b2), wave covers N-tiles [wv*2, wv*2+2) ----
    f32x4 acc[2][2];
    #pragma unroll
    for (int mt = 0; mt < 2; mt++)
        #pragma unroll
        for (int p = 0; p < 2; p++) acc[mt][p] = (f32x4){0.f,0.f,0.f,0.f};

    #pragma unroll
    for (int kt = 0; kt < 16; kt++){
        s16x8 a0 = *(const s16x8*)(Hs + SWZ5(c15,      kt * 32 + q * 8));
        s16x8 a1v= *(const s16x8*)(Hs + SWZ5(16 + c15, kt * 32 + q * 8));
        #pragma unroll
        for (int p = 0; p < 2; p++){
            int ntp = wv * 2 + p;
            s16x8 bfr = *(const s16x8*)(W2pk + (((ntp << 4) + kt) * 64 + lane) * 8);
            acc[0][p] = __builtin_amdgcn_mfma_f32_16x16x32_bf16(a0,  bfr, acc[0][p], 0, 0, 0);
            acc[1][p] = __builtin_amdgcn_mfma_f32_16x16x32_bf16(a1v, bfr, acc[1][p], 0, 0, 0);
        }
    }
    #pragma unroll
    for (int mt = 0; mt < 2; mt++)
        #pragma unroll
        for (int p = 0; p < 2; p++){
            int col = (wv * 2 + p) * 16 + c15;
            float gv = gamma[col], bv = b2[col];
            #pragma unroll
            for (int r = 0; r < 4; r++){
                int row = m0b + mt * 16 + 4 * q + r;
                float* pr = row_addr(ct_res, x_res, row, split) + col;
                *pr = *pr + gv * (acc[mt][p][r] + bv);
            }
        }
}

// ---------------- final x: out_x += gamma1 * upsampled carrier (in place) ----------------
__global__ void final_x_kernel(float* out_x, const float* __restrict__ out_ct,
                               const float* __restrict__ g1)
{
    int idx = blockIdx.x * 256 + threadIdx.x;   // over 4096*49*128
    int w   = idx / (49 * 128);
    int rem = idx % (49 * 128);
    int p   = rem >> 7;
    int c   = rem & 127;
    int a = p / 7, bc = p % 7;
    int s = ((a * 4) / 7) * 4 + (bc * 4) / 7;
    out_x[idx] = out_x[idx] + g1[c] * out_ct[((size_t)w * 16 + s) * 128 + c];
}

extern "C" void kernel_launch(void* const* d_in, const int* in_sizes, int n_in,
                              void* d_out, int out_size, void* d_ws, size_t ws_size,
                              hipStream_t stream)
{
    const float* x_in        = (const float*)d_in[0];
    const float* ct_in       = (const float*)d_in[1];
    const float* pe_w1       = (const float*)d_in[2];
    const float* pe_b1       = (const float*)d_in[3];
    const float* pe_w2       = (const float*)d_in[4];
    const float* hpe_w1      = (const float*)d_in[5];
    const float* hpe_b1      = (const float*)d_in[6];
    const float* hpe_w2      = (const float*)d_in[7];
    const float* n1_g        = (const float*)d_in[8];
    const float* n1_b        = (const float*)d_in[9];
    const float* n2_g        = (const float*)d_in[10];
    const float* n2_b        = (const float*)d_in[11];
    const float* hn1_g       = (const float*)d_in[12];
    const float* hn1_b       = (const float*)d_in[13];
    const float* hn2_g       = (const float*)d_in[14];
    const float* hn2_b       = (const float*)d_in[15];
    const float* attn_qkv_w  = (const float*)d_in[16];
    const float* attn_proj_w = (const float*)d_in[17];
    const float* attn_proj_b = (const float*)d_in[18];
    const float* attn_cpb_w1 = (const float*)d_in[19];
    const float* attn_cpb_b1 = (const float*)d_in[20];
    const float* attn_cpb_w2 = (const float*)d_in[21];
    const float* hat_qkv_w   = (const float*)d_in[22];
    const float* hat_proj_w  = (const float*)d_in[23];
    const float* hat_proj_b  = (const float*)d_in[24];
    const float* hat_cpb_w1  = (const float*)d_in[25];
    const float* hat_cpb_b1  = (const float*)d_in[26];
    const float* hat_cpb_w2  = (const float*)d_in[27];
    const float* mlp_w1      = (const float*)d_in[28];
    const float* mlp_b1      = (const float*)d_in[29];
    const float* mlp_w2      = (const float*)d_in[30];
    const float* mlp_b2      = (const float*)d_in[31];
    const float* hmlp_w1     = (const float*)d_in[32];
    const float* hmlp_b1     = (const float*)d_in[33];
    const float* hmlp_w2     = (const float*)d_in[34];
    const float* hmlp_b2     = (const float*)d_in[35];
    const float* gamma1      = (const float*)d_in[36];
    const float* gamma2      = (const float*)d_in[37];
    const float* gamma3      = (const float*)d_in[38];
    const float* gamma4      = (const float*)d_in[39];

    const int M2 = 4096 * 65;   // 266240 concat tokens
    const int MC = 256 * 256;   // 65536 carrier tokens

    // residuals live in d_out (float). The out_x region (102.8MB) is dead until
    // win_attn_mfma writes it; during the carrier phase it holds bf16 qkv
    // (50.3MB) + hat-path packed weights (~0.4MB).
    float* out_x  = (float*)d_out;                        // [4096*49][128]
    float* out_ct = out_x + (size_t)4096 * 49 * 128;      // [65536][128] carrier residual

    ushort* qkvB    = (ushort*)out_x;                     // [65536][384] bf16
    ushort* Whq_pk  = qkvB   + (size_t)MC * 384;          // 24*4*64*8 = 49152
    ushort* Whp_pk  = Whq_pk + 24 * 4 * 64 * 8;           //  8*4*64*8 = 16384
    ushort* W1c_pk  = Whp_pk +  8 * 4 * 64 * 8;           // 32*4*64*8 = 65536
    ushort* W2c_pk  = W1c_pk + 32 * 4 * 64 * 8;           // 8*16*64*8 = 65536

    // workspace: one 33.6MB timeshared buffer + small tables (~34 MB total)
    char* p = (char*)d_ws;
    float* S     = (float*)p; p += (size_t)MC * 128 * 4;  // carrier attn-out, then main packs
    float* pe    = (float*)p; p += 49 * 128 * 4;
    float* hpe   = (float*)p; p += 256 * 128 * 4;
    float* btbl7 = (float*)p; p += 169 * 4 * 4;
    float* btbl16= (float*)p; p += 961 * 4 * 4;

    // main-path packed weights — carved from S (dead after carrier proj)
    ushort* Wqkv_pk = (ushort*)S;                 // 24*4*64*8 = 49152
    ushort* Wp_pk   = Wqkv_pk + 24 * 4 * 64 * 8;  //  8*4*64*8 = 16384
    ushort* W1m_pk  = Wp_pk   +  8 * 4 * 64 * 8;  // 65536
    ushort* W2m_pk  = W1m_pk  + 32 * 4 * 64 * 8;  // 65536

    posemb_kernel<<<49, 128, 0, stream>>>(pe_w1, pe_b1, pe_w2, pe, 7);
    posemb_kernel<<<256, 128, 0, stream>>>(hpe_w1, hpe_b1, hpe_w2, hpe, 16);
    cpb_kernel<<<3, 64, 0, stream>>>(attn_cpb_w1, attn_cpb_b1, attn_cpb_w2, btbl7, 7);
    cpb_kernel<<<16, 64, 0, stream>>>(hat_cpb_w1, hat_cpb_b1, hat_cpb_w2, btbl16, 16);

    // ---- pack hat-path weights into out_x region (dead until win_attn) ----
    pack_w_kernel<<<192, 256, 0, stream>>>(hat_qkv_w, Whq_pk, 384, 4);
    pack_w_kernel<<<64, 256, 0, stream>>>(hat_proj_w, Whp_pk, 128, 4);
    pack_w_kernel<<<256, 256, 0, stream>>>(hmlp_w1, W1c_pk, 512, 4);
    pack_w_kernel<<<256, 256, 0, stream>>>(hmlp_w2, W2c_pk, 128, 16);

    // ---- carrier path (residual = out_ct), fully MFMA ----
    ct_init_kernel<<<(MC * 128) / 256, 256, 0, stream>>>(ct_in, hpe, out_ct);
    qkv_mfma<<<MC / 32, 256, 0, stream>>>(out_ct, hn1_g, hn1_b, Whq_pk, qkvB);
    carrier_attn_mfma<<<256 * 4, 256, 0, stream>>>(qkvB, btbl16, S);
    res_gemm_mfma<<<MC / 32, 256, 0, stream>>>(S, out_ct, nullptr, 0,
                                               Whp_pk, hat_proj_b, gamma1);
    mlp_mfma<<<MC / 32, 256, 0, stream>>>(out_ct, nullptr, 0, hn2_g, hn2_b,
                                          W1c_pk, hmlp_b1, W2c_pk, hmlp_b2, gamma2);

    // ---- pack main-path weights into S (dead now) ----
    pack_w_kernel<<<192, 256, 0, stream>>>(attn_qkv_w, Wqkv_pk, 384, 4);
    pack_w_kernel<<<64, 256, 0, stream>>>(attn_proj_w, Wp_pk, 128, 4);
    pack_w_kernel<<<256, 256, 0, stream>>>(mlp_w1, W1m_pk, 512, 4);
    pack_w_kernel<<<256, 256, 0, stream>>>(mlp_w2, W2m_pk, 128, 16);

    // ---- main path (x_init fused into win_attn) ----
    win_attn_mfma<<<4096, 320, 0, stream>>>(out_ct, out_x, x_in, pe,
                                            Wqkv_pk, n1_g, n1_b,
                                            btbl7, Wp_pk, attn_proj_b, gamma3);
    mlp_mfma<<<M2 / 32, 256, 0, stream>>>(out_ct, out_x, 1, n2_g, n2_b,
                                          W1m_pk, mlp_b1, W2m_pk, mlp_b2, gamma4);

    // ---- finalize (out_ct already holds final carrier residual) ----
    final_x_kernel<<<(4096 * 49 * 128) / 256, 256, 0, stream>>>(out_x, out_ct, gamma1);
}

// Round 8
// 1287.691 us; speedup vs baseline: 1.0808x; 1.0808x over previous
//
#include <hip/hip_runtime.h>
#include <hip/hip_bf16.h>
#include <math.h>

typedef __hip_bfloat16 bf16;
typedef unsigned short ushort;
typedef __attribute__((ext_vector_type(8))) short s16x8;   // 8 bf16 (4 VGPRs)
typedef __attribute__((ext_vector_type(4))) float f32x4;

__device__ __forceinline__ float b2f(bf16 v){ return __bfloat162float(v); }
__device__ __forceinline__ bf16  f2b(float v){ return __float2bfloat16(v); }
__device__ __forceinline__ ushort f2u(float v){
    union { bf16 b; ushort u; } cv; cv.b = __float2bfloat16(v); return cv.u;
}

// residual row address in the split d_out layout:
// token t in concat space (w = t/65, r = t%65): r<16 -> out_ct slot (w*16+r),
// else out_x row (w*49 + r-16). split==0: contiguous ct rows (carrier path).
__device__ __forceinline__ float* row_addr(float* ct, float* x, int t, int split)
{
    if (!split) return ct + (size_t)t * 128;
    int w = t / 65, r = t - w * 65;
    if (r < 16) return ct + ((size_t)w * 16 + r) * 128;
    return x + ((size_t)w * 49 + (r - 16)) * 128;
}

// ---------------- posemb MLP: out[seq][128] = relu(t@w1+b1)@w2 (fp32) ----------------
__global__ void posemb_kernel(const float* __restrict__ w1, const float* __restrict__ b1,
                              const float* __restrict__ w2, float* __restrict__ out, int s)
{
    int i = blockIdx.x;
    int c = threadIdx.x;
    int half = s / 2;
    float t0 = (float)(i / s - half) / (float)half;
    float t1 = (float)(i % s - half) / (float)half;
    float acc = 0.f;
    for (int k = 0; k < 512; k++){
        float h = t0 * w1[k] + t1 * w1[512 + k] + b1[k];
        h = fmaxf(h, 0.f);
        acc += h * w2[k * 128 + c];
    }
    out[i * 128 + c] = acc;
}

// ------------- CPB table: tbl[(2ws-1)^2][4] = 16*sigmoid(relu(t@w1+b1)@w2) -------------
__global__ void cpb_kernel(const float* __restrict__ w1, const float* __restrict__ b1,
                           const float* __restrict__ w2, float* __restrict__ tbl, int ws)
{
    int d = 2 * ws - 1;
    int ne = d * d;
    int e = blockIdx.x * 64 + threadIdx.x;
    if (e >= ne) return;
    float rh = (float)(e / d - (ws - 1));
    float rw = (float)(e % d - (ws - 1));
    float t0 = rh / (float)(ws - 1) * 8.f;
    float t1 = rw / (float)(ws - 1) * 8.f;
    float s0 = (t0 > 0.f) ? 1.f : ((t0 < 0.f) ? -1.f : 0.f);
    float s1 = (t1 > 0.f) ? 1.f : ((t1 < 0.f) ? -1.f : 0.f);
    t0 = s0 * log2f(fabsf(t0) + 1.f) * (1.f / 3.f);
    t1 = s1 * log2f(fabsf(t1) + 1.f) * (1.f / 3.f);
    float acc[4] = {0.f, 0.f, 0.f, 0.f};
    for (int k = 0; k < 512; k++){
        float h = t0 * w1[k] + t1 * w1[512 + k] + b1[k];
        h = fmaxf(h, 0.f);
        #pragma unroll
        for (int hh = 0; hh < 4; hh++) acc[hh] += h * w2[k * 4 + hh];
    }
    #pragma unroll
    for (int hh = 0; hh < 4; hh++)
        tbl[e * 4 + hh] = 16.f / (1.f + expf(-acc[hh]));
}

// ---------------- ct_init: out_ct = ct + hpe ----------------
__global__ void ct_init_kernel(const float* __restrict__ ct, const float* __restrict__ hpe,
                               float* __restrict__ out_ct)
{
    int idx = blockIdx.x * 256 + threadIdx.x;      // over 65536*128
    out_ct[idx] = ct[idx] + hpe[idx % (256 * 128)];
}

// ---------------- pack W[K][N] (fp32) into MFMA B-frag order (bf16) ----------------
// out[((nt*KT + kt)*64 + lane)*8 + j] = bf16(W[(kt*32 + (lane>>4)*8 + j)*N + nt*16 + (lane&15)])
__global__ void pack_w_kernel(const float* __restrict__ W, ushort* __restrict__ out,
                              int N, int KT)
{
    int idx = blockIdx.x * 256 + threadIdx.x;
    int j   = idx & 7;
    int l   = (idx >> 3) & 63;
    int rest= idx >> 9;
    int kt  = rest % KT;
    int nt  = rest / KT;
    int k   = kt * 32 + ((l >> 4) << 3) + j;
    int c   = nt * 16 + (l & 15);
    out[idx] = f2u(W[(size_t)k * N + c]);
}

#define SWZ(r,c)  ((r)*128 + ((c) ^ (((r)&7)<<3)))
#define SWZ5(r,c) ((r)*512 + ((c) ^ (((r)&7)<<3)))

// ---------------- carrier fused LN + QKV GEMM (MFMA), bf16 out ----------------
__global__ __launch_bounds__(256) void qkv_mfma(
    const float* __restrict__ ct_res,
    const float* __restrict__ g, const float* __restrict__ b,
    const ushort* __restrict__ Wpk,       // [24][4][64][8]
    ushort* __restrict__ qkvB)            // [65536][384] bf16
{
    __shared__ ushort Xs[32*128];
    int m0b = blockIdx.x * 32;
    int tid = threadIdx.x;
    int wv  = tid >> 6, lane = tid & 63;
    int q   = lane >> 4, c15 = lane & 15;

    for (int t = wv; t < 32; t += 4){
        const float* row = ct_res + (size_t)(m0b + t) * 128;
        float v0 = row[lane], v1 = row[lane + 64];
        float s = v0 + v1, s2 = v0 * v0 + v1 * v1;
        #pragma unroll
        for (int off = 32; off >= 1; off >>= 1){
            s  += __shfl_xor(s,  off, 64);
            s2 += __shfl_xor(s2, off, 64);
        }
        float mean = s * (1.f / 128.f);
        float var  = s2 * (1.f / 128.f) - mean * mean;
        float r = rsqrtf(var + 1e-5f);
        Xs[SWZ(t, lane)]      = f2u((v0 - mean) * r * g[lane]      + b[lane]);
        Xs[SWZ(t, lane + 64)] = f2u((v1 - mean) * r * g[lane + 64] + b[lane + 64]);
    }
    __syncthreads();

    s16x8 a1[2][4];
    #pragma unroll
    for (int mt = 0; mt < 2; mt++)
        #pragma unroll
        for (int kt = 0; kt < 4; kt++)
            a1[mt][kt] = *(const s16x8*)(Xs + SWZ(mt * 16 + c15, kt * 32 + q * 8));

    #pragma unroll
    for (int nt0 = 0; nt0 < 6; nt0++){
        int nt = wv * 6 + nt0;
        f32x4 acc0 = {0.f,0.f,0.f,0.f}, acc1 = {0.f,0.f,0.f,0.f};
        #pragma unroll
        for (int kt = 0; kt < 4; kt++){
            s16x8 bfr = *(const s16x8*)(Wpk + (((nt << 2) + kt) * 64 + lane) * 8);
            acc0 = __builtin_amdgcn_mfma_f32_16x16x32_bf16(a1[0][kt], bfr, acc0, 0, 0, 0);
            acc1 = __builtin_amdgcn_mfma_f32_16x16x32_bf16(a1[1][kt], bfr, acc1, 0, 0, 0);
        }
        #pragma unroll
        for (int r = 0; r < 4; r++){
            qkvB[(size_t)(m0b +      4 * q + r) * 384 + nt * 16 + c15] = f2u(acc0[r]);
            qkvB[(size_t)(m0b + 16 + 4 * q + r) * 384 + nt * 16 + c15] = f2u(acc1[r]);
        }
    }
}

// ------- main-path fused LN + QKV GEMM over concat tokens (split sources) -------
// base = w0*65; writes qkvS[local_token][384] bf16 for 32 tokens/block.
__global__ __launch_bounds__(256) void qkv_split_mfma(
    const float* __restrict__ ct_res,
    const float* __restrict__ x_in, const float* __restrict__ pe,
    int base,
    const float* __restrict__ g, const float* __restrict__ b,
    const ushort* __restrict__ Wpk,       // [24][4][64][8]
    ushort* __restrict__ qkvS)
{
    __shared__ ushort Xs[32*128];
    int m0b = blockIdx.x * 32;
    int tid = threadIdx.x;
    int wv  = tid >> 6, lane = tid & 63;
    int q   = lane >> 4, c15 = lane & 15;

    for (int t = wv; t < 32; t += 4){
        int T = base + m0b + t;
        int wloc = T / 65, r = T - wloc * 65;
        float v0, v1;
        if (r < 16){
            const float* row = ct_res + ((size_t)wloc * 16 + r) * 128;
            v0 = row[lane]; v1 = row[lane + 64];
        } else {
            const float* row = x_in + ((size_t)wloc * 49 + (r - 16)) * 128;
            const float* pr  = pe + (r - 16) * 128;
            v0 = row[lane] + pr[lane];
            v1 = row[lane + 64] + pr[lane + 64];
        }
        float s = v0 + v1, s2 = v0 * v0 + v1 * v1;
        #pragma unroll
        for (int off = 32; off >= 1; off >>= 1){
            s  += __shfl_xor(s,  off, 64);
            s2 += __shfl_xor(s2, off, 64);
        }
        float mean = s * (1.f / 128.f);
        float var  = s2 * (1.f / 128.f) - mean * mean;
        float rr = rsqrtf(var + 1e-5f);
        Xs[SWZ(t, lane)]      = f2u((v0 - mean) * rr * g[lane]      + b[lane]);
        Xs[SWZ(t, lane + 64)] = f2u((v1 - mean) * rr * g[lane + 64] + b[lane + 64]);
    }
    __syncthreads();

    s16x8 a1[2][4];
    #pragma unroll
    for (int mt = 0; mt < 2; mt++)
        #pragma unroll
        for (int kt = 0; kt < 4; kt++)
            a1[mt][kt] = *(const s16x8*)(Xs + SWZ(mt * 16 + c15, kt * 32 + q * 8));

    #pragma unroll
    for (int nt0 = 0; nt0 < 6; nt0++){
        int nt = wv * 6 + nt0;
        f32x4 acc0 = {0.f,0.f,0.f,0.f}, acc1 = {0.f,0.f,0.f,0.f};
        #pragma unroll
        for (int kt = 0; kt < 4; kt++){
            s16x8 bfr = *(const s16x8*)(Wpk + (((nt << 2) + kt) * 64 + lane) * 8);
            acc0 = __builtin_amdgcn_mfma_f32_16x16x32_bf16(a1[0][kt], bfr, acc0, 0, 0, 0);
            acc1 = __builtin_amdgcn_mfma_f32_16x16x32_bf16(a1[1][kt], bfr, acc1, 0, 0, 0);
        }
        #pragma unroll
        for (int r = 0; r < 4; r++){
            qkvS[(size_t)(m0b +      4 * q + r) * 384 + nt * 16 + c15] = f2u(acc0[r]);
            qkvS[(size_t)(m0b + 16 + 4 * q + r) * 384 + nt * 16 + c15] = f2u(acc1[r]);
        }
    }
}

// ---------------- carrier attention via MFMA: one block per (b, head) ----------------
__global__ __launch_bounds__(256) void carrier_attn_mfma(
    const ushort* __restrict__ qkvB,      // [65536][384] bf16
    const float* __restrict__ btbl,       // [961][4]
    float* __restrict__ out)              // [65536][128] float (attn out)
{
    __shared__ ushort Kh[256 * 40];       // [key][d32]   stride 40
    __shared__ ushort Vt[32 * 264];       // [d32][key]   stride 264
    __shared__ ushort Pb[4][16 * 264];    // per-wave [row16][key] stride 264
    __shared__ float  tbl[961];

    int bx = blockIdx.x;
    int b  = bx >> 2, h = bx & 3;
    int tid = threadIdx.x;
    int wv  = tid >> 6, lane = tid & 63;
    int q   = lane >> 4, c15 = lane & 15;
    const float scale = 0.17677669529663688f;   // 1/sqrt(32)

    // stage K (row-major) and V (transposed) for this (b,h)
    for (int idx = tid; idx < 256 * 8; idx += 256){
        int tok = idx >> 3, seg = idx & 7;
        size_t base = (size_t)(b * 256 + tok) * 384 + h * 32 + seg * 4;
        uint2 kk = *(const uint2*)(qkvB + base + 128);
        uint2 vv = *(const uint2*)(qkvB + base + 256);
        *(uint2*)(Kh + tok * 40 + seg * 4) = kk;
        ushort* vp = (ushort*)&vv;
        #pragma unroll
        for (int k2 = 0; k2 < 4; k2++) Vt[(seg * 4 + k2) * 264 + tok] = vp[k2];
    }
    for (int i = tid; i < 961; i += 256) tbl[i] = btbl[i * 4 + h];
    __syncthreads();

    ushort* Pw = Pb[wv];
    for (int s = 0; s < 4; s++){
        int st = wv * 4 + s, r0 = st * 16;
        s16x8 a = *(const s16x8*)(qkvB + (size_t)(b * 256 + r0 + c15) * 384 + h * 32 + q * 8);
        f32x4 sc[16];
        #pragma unroll
        for (int nt = 0; nt < 16; nt++){
            s16x8 bfr = *(const s16x8*)(Kh + (nt * 16 + c15) * 40 + q * 8);
            f32x4 z = {0.f,0.f,0.f,0.f};
            sc[nt] = __builtin_amdgcn_mfma_f32_16x16x32_bf16(a, bfr, z, 0, 0, 0);
        }
        float linv_r[4];
        #pragma unroll
        for (int r = 0; r < 4; r++){
            int rr = 4 * q + r;
            float sv[16];
            #pragma unroll
            for (int nt = 0; nt < 16; nt++)
                sv[nt] = sc[nt][r] * scale + tbl[(st - nt + 15) * 31 + (rr - c15 + 15)];
            float m = sv[0];
            #pragma unroll
            for (int nt = 1; nt < 16; nt++) m = fmaxf(m, sv[nt]);
            #pragma unroll
            for (int off = 8; off >= 1; off >>= 1) m = fmaxf(m, __shfl_xor(m, off, 64));
            float l = 0.f;
            #pragma unroll
            for (int nt = 0; nt < 16; nt++){
                float p = __expf(sv[nt] - m);
                sv[nt] = p; l += p;
            }
            #pragma unroll
            for (int off = 8; off >= 1; off >>= 1) l += __shfl_xor(l, off, 64);
            linv_r[r] = 1.f / l;
            #pragma unroll
            for (int nt = 0; nt < 16; nt++)
                Pw[rr * 264 + nt * 16 + c15] = f2u(sv[nt]);
        }
        // PV: O[16][32] = P[16][256] @ V[256][32]
        #pragma unroll
        for (int ntv = 0; ntv < 2; ntv++){
            f32x4 acc = {0.f,0.f,0.f,0.f};
            #pragma unroll
            for (int kt = 0; kt < 8; kt++){
                s16x8 ap = *(const s16x8*)(Pw + c15 * 264 + kt * 32 + q * 8);
                s16x8 bv = *(const s16x8*)(Vt + (ntv * 16 + c15) * 264 + kt * 32 + q * 8);
                acc = __builtin_amdgcn_mfma_f32_16x16x32_bf16(ap, bv, acc, 0, 0, 0);
            }
            #pragma unroll
            for (int r = 0; r < 4; r++)
                out[(size_t)(b * 256 + r0 + 4 * q + r) * 128 + h * 32 + ntv * 16 + c15]
                    = acc[r] * linv_r[r];
        }
    }
}

// ------------- residual GEMM (MFMA): res += gamma*(src@W + bias), K=N=128 -------------
__global__ __launch_bounds__(256) void res_gemm_mfma(
    const float* __restrict__ src, float* ct_res, float* x_res, int split,
    const ushort* __restrict__ Wpk,       // [8][4][64][8]
    const float* __restrict__ bias, const float* __restrict__ gamma)
{
    __shared__ ushort Xs[32*128];
    int m0b = blockIdx.x * 32;
    int tid = threadIdx.x;
    int wv  = tid >> 6, lane = tid & 63;
    int q   = lane >> 4, c15 = lane & 15;

    for (int t = wv; t < 32; t += 4){
        const float* row = src + (size_t)(m0b + t) * 128;
        Xs[SWZ(t, lane)]      = f2u(row[lane]);
        Xs[SWZ(t, lane + 64)] = f2u(row[lane + 64]);
    }
    __syncthreads();

    s16x8 a1[2][4];
    #pragma unroll
    for (int mt = 0; mt < 2; mt++)
        #pragma unroll
        for (int kt = 0; kt < 4; kt++)
            a1[mt][kt] = *(const s16x8*)(Xs + SWZ(mt * 16 + c15, kt * 32 + q * 8));

    f32x4 acc[2][2];
    #pragma unroll
    for (int mt = 0; mt < 2; mt++)
        #pragma unroll
        for (int p = 0; p < 2; p++) acc[mt][p] = (f32x4){0.f,0.f,0.f,0.f};

    #pragma unroll
    for (int kt = 0; kt < 4; kt++)
        #pragma unroll
        for (int p = 0; p < 2; p++){
            int nt = wv * 2 + p;
            s16x8 bfr = *(const s16x8*)(Wpk + (((nt << 2) + kt) * 64 + lane) * 8);
            acc[0][p] = __builtin_amdgcn_mfma_f32_16x16x32_bf16(a1[0][kt], bfr, acc[0][p], 0, 0, 0);
            acc[1][p] = __builtin_amdgcn_mfma_f32_16x16x32_bf16(a1[1][kt], bfr, acc[1][p], 0, 0, 0);
        }

    #pragma unroll
    for (int mt = 0; mt < 2; mt++)
        #pragma unroll
        for (int p = 0; p < 2; p++){
            int col = (wv * 2 + p) * 16 + c15;
            float gv = gamma[col], bv = bias[col];
            #pragma unroll
            for (int r = 0; r < 4; r++){
                int row = m0b + mt * 16 + 4 * q + r;
                float* pr = row_addr(ct_res, x_res, row, split) + col;
                *pr = *pr + gv * (acc[mt][p][r] + bv);
            }
        }
}

// ---------------- lean main-path window attention (qkv precomputed) ----------------
// one block per window, 5 waves x one 16-row strip. Per head: stage K/V with
// plain coalesced loads, Q A-frags direct from global, bias table in LDS.
// LDS 38.8KB -> 4 blocks/CU.
__global__ __launch_bounds__(320) void win_attn2(
    float* ct_res, float* out_x,
    const float* __restrict__ x_in, const float* __restrict__ pe,
    int w0,
    const ushort* __restrict__ qkvS,     // [NW*65][384] bf16 (chunk-local rows)
    const float* __restrict__ btbl,      // [169][4]
    const ushort* __restrict__ Wp_pk,    // [8][4][64][8]
    const float* __restrict__ bp, const float* __restrict__ g3)
{
    __shared__ ushort Kh[80*40];    // [token][d32]
    __shared__ ushort Vt[32*104];   // [d32][key]  keys padded to 96
    __shared__ ushort Pb[80*104];   // [row][key]  strip-private rows
    __shared__ ushort Ob[5*16*40];  // wave-private [16][d32]
    __shared__ float  stbl[169*4];

    int wi  = blockIdx.x;
    int w   = w0 + wi;
    int tid = threadIdx.x;
    int wv  = tid >> 6, lane = tid & 63;
    int q   = lane >> 4, c15 = lane & 15;
    int m0  = wv * 16;
    const ushort* qrow = qkvS + (size_t)wi * 65 * 384;

    // one-time zero pads + bias table
    for (int i = tid; i < 15 * 40; i += 320) Kh[65 * 40 + i] = 0;        // K rows 65..79
    for (int i = tid; i < 32 * 39; i += 320){                            // V keys 65..103
        int d = i / 39, t = 65 + (i - d * 39);
        Vt[d * 104 + t] = 0;
    }
    for (int i = tid; i < 80 * 16; i += 320) Pb[(i >> 4) * 104 + 80 + (i & 15)] = 0;
    for (int i = tid; i < 169 * 4; i += 320) stbl[i] = btbl[i];

    // rel-bias indices for this lane's (row,col) pattern
    int  bidx[5][4];
    bool cvalid[5];
    {
        int cdiv[5], cmod[5]; bool cb[5];
        #pragma unroll
        for (int nt = 0; nt < 5; nt++){
            int col = nt * 16 + c15;
            cvalid[nt] = col < 65;
            cb[nt] = (col >= 16) && (col < 65);
            int wq = col - 16; if (wq < 0) wq = 0;
            cdiv[nt] = wq / 7; cmod[nt] = wq - cdiv[nt] * 7;
        }
        #pragma unroll
        for (int r = 0; r < 4; r++){
            int row = m0 + 4 * q + r;
            bool rb = (row >= 16) && (row < 65);
            int wp = row - 16; if (wp < 0) wp = 0;
            int rdiv = wp / 7, rmod = wp - rdiv * 7;
            #pragma unroll
            for (int nt = 0; nt < 5; nt++){
                if (rb && cb[nt]){
                    int di = rdiv - cdiv[nt] + 6;
                    int dj = rmod - cmod[nt] + 6;
                    bidx[nt][r] = (di * 13 + dj) * 4;
                } else bidx[nt][r] = -1;
            }
        }
    }
    __syncthreads();

    f32x4 pacc[8];
    #pragma unroll
    for (int i = 0; i < 8; i++) pacc[i] = (f32x4){0.f, 0.f, 0.f, 0.f};
    ushort* Obw = Ob + wv * 640;

    int qr = m0 + c15; if (qr > 64) qr = 64;    // clamp pad rows (outputs discarded)

    for (int h = 0; h < 4; h++){
        // ---- stage K (row-major) and V (transposed) for head h ----
        for (int idx = tid; idx < 65 * 8; idx += 320){
            int tok = idx >> 3, seg = idx & 7;
            const ushort* src = qrow + (size_t)tok * 384 + h * 32 + seg * 4;
            uint2 kk = *(const uint2*)(src + 128);
            uint2 vv = *(const uint2*)(src + 256);
            *(uint2*)(Kh + tok * 40 + seg * 4) = kk;
            ushort* vp = (ushort*)&vv;
            #pragma unroll
            for (int k2 = 0; k2 < 4; k2++) Vt[(seg * 4 + k2) * 104 + tok] = vp[k2];
        }
        __syncthreads();

        // ---- scores: Q direct from global, K from LDS ----
        s16x8 aq = *(const s16x8*)(qrow + (size_t)qr * 384 + h * 32 + q * 8);
        f32x4 sc[5];
        #pragma unroll
        for (int nt = 0; nt < 5; nt++){
            s16x8 b = *(const s16x8*)(Kh + (nt * 16 + c15) * 40 + q * 8);
            f32x4 z = {0.f, 0.f, 0.f, 0.f};
            sc[nt] = __builtin_amdgcn_mfma_f32_16x16x32_bf16(aq, b, z, 0, 0, 0);
        }
        float linv_r[4];
        #pragma unroll
        for (int r = 0; r < 4; r++){
            float sv[5];
            #pragma unroll
            for (int nt = 0; nt < 5; nt++){
                float x = sc[nt][r] * 0.17677669529663688f;
                if (bidx[nt][r] >= 0) x += stbl[bidx[nt][r] + h];
                sv[nt] = cvalid[nt] ? x : -1e30f;
            }
            float m = sv[0];
            #pragma unroll
            for (int nt = 1; nt < 5; nt++) m = fmaxf(m, sv[nt]);
            #pragma unroll
            for (int off = 8; off >= 1; off >>= 1) m = fmaxf(m, __shfl_xor(m, off, 64));
            float l = 0.f;
            #pragma unroll
            for (int nt = 0; nt < 5; nt++){
                float p = cvalid[nt] ? __expf(sv[nt] - m) : 0.f;
                sv[nt] = p; l += p;
            }
            #pragma unroll
            for (int off = 8; off >= 1; off >>= 1) l += __shfl_xor(l, off, 64);
            linv_r[r] = 1.f / l;
            int row = m0 + 4 * q + r;
            #pragma unroll
            for (int nt = 0; nt < 5; nt++)
                Pb[row * 104 + nt * 16 + c15] = f2u(sv[nt]);
        }

        // ---- PV: O[strip][32] = P[strip][96] @ V[96][32] ----
        #pragma unroll
        for (int ntv = 0; ntv < 2; ntv++){
            f32x4 acc = {0.f, 0.f, 0.f, 0.f};
            #pragma unroll
            for (int kt = 0; kt < 3; kt++){
                s16x8 a = *(const s16x8*)(Pb + (m0 + c15) * 104 + kt * 32 + q * 8);
                s16x8 b = *(const s16x8*)(Vt + (ntv * 16 + c15) * 104 + kt * 32 + q * 8);
                acc = __builtin_amdgcn_mfma_f32_16x16x32_bf16(a, b, acc, 0, 0, 0);
            }
            #pragma unroll
            for (int r = 0; r < 4; r++)
                Obw[(4 * q + r) * 40 + ntv * 16 + c15] = f2u(acc[r] * linv_r[r]);
        }

        // ---- proj partial: pacc += O(strip, head h's 32ch) @ Wp[h*32:,:] ----
        s16x8 ao = *(const s16x8*)(Obw + c15 * 40 + q * 8);
        #pragma unroll
        for (int ntp = 0; ntp < 8; ntp++){
            s16x8 b = *(const s16x8*)(Wp_pk + (((ntp << 2) + h) * 64 + lane) * 8);
            pacc[ntp] = __builtin_amdgcn_mfma_f32_16x16x32_bf16(ao, b, pacc[ntp], 0, 0, 0);
        }
        __syncthreads();   // before next head's stage overwrites Kh/Vt
    }

    // ---- residual update: ct rows RMW out_ct; x rows = x_in + pe + g3*proj ----
    #pragma unroll
    for (int ntp = 0; ntp < 8; ntp++){
        int col = ntp * 16 + c15;
        float gv = g3[col], bv = bp[col];
        #pragma unroll
        for (int r = 0; r < 4; r++){
            int row = m0 + 4 * q + r;
            if (row < 65){
                float upd = gv * (pacc[ntp][r] + bv);
                if (row < 16){
                    float* pr = ct_res + ((size_t)w * 16 + row) * 128 + col;
                    *pr = *pr + upd;
                } else {
                    size_t xi = ((size_t)w * 49 + (row - 16)) * 128 + col;
                    out_x[xi] = x_in[xi] + pe[(row - 16) * 128 + col] + upd;
                }
            }
        }
    }
}

// ---------------- fused LN + MLP via MFMA (+gamma residual), 32 tokens/block ----------------
__global__ __launch_bounds__(256) void mlp_mfma(
    float* ct_res, float* x_res, int split,
    const float* __restrict__ g,  const float* __restrict__ b,
    const ushort* __restrict__ W1pk,  // [32][4][64][8]  bf16 frags (N=512,KT=4)
    const float* __restrict__ b1,
    const ushort* __restrict__ W2pk,  // [8][16][64][8]  bf16 frags (N=128,KT=16)
    const float* __restrict__ b2,
    const float* __restrict__ gamma)
{
    __shared__ ushort Xs[32*128];     // LN'd tokens, XOR-swizzled
    __shared__ ushort Hs[32*512];     // gelu hidden, XOR-swizzled

    int m0b = blockIdx.x * 32;
    int tid = threadIdx.x;
    int wv  = tid >> 6, lane = tid & 63;
    int q   = lane >> 4, c15 = lane & 15;

    // ---- LN into Xs ----
    for (int t = wv; t < 32; t += 4){
        const float* row = row_addr(ct_res, x_res, m0b + t, split);
        float v0 = row[lane], v1 = row[lane + 64];
        float s = v0 + v1, s2 = v0 * v0 + v1 * v1;
        #pragma unroll
        for (int off = 32; off >= 1; off >>= 1){
            s  += __shfl_xor(s,  off, 64);
            s2 += __shfl_xor(s2, off, 64);
        }
        float mean = s * (1.f / 128.f);
        float var  = s2 * (1.f / 128.f) - mean * mean;
        float r = rsqrtf(var + 1e-5f);
        Xs[SWZ(t, lane)]      = f2u((v0 - mean) * r * g[lane]      + b[lane]);
        Xs[SWZ(t, lane + 64)] = f2u((v1 - mean) * r * g[lane + 64] + b[lane + 64]);
    }
    __syncthreads();

    // ---- GEMM1: H = gelu(X @ W1 + b1), wave covers N-tiles [wv*8, wv*8+8) ----
    s16x8 a1[2][4];
    #pragma unroll
    for (int mt = 0; mt < 2; mt++)
        #pragma unroll
        for (int kt = 0; kt < 4; kt++)
            a1[mt][kt] = *(const s16x8*)(Xs + SWZ(mt * 16 + c15, kt * 32 + q * 8));

    #pragma unroll
    for (int nt0 = 0; nt0 < 8; nt0++){
        int nt = wv * 8 + nt0;
        f32x4 acc0 = {0.f,0.f,0.f,0.f}, acc1 = {0.f,0.f,0.f,0.f};
        #pragma unroll
        for (int kt = 0; kt < 4; kt++){
            s16x8 bfr = *(const s16x8*)(W1pk + (((nt << 2) + kt) * 64 + lane) * 8);
            acc0 = __builtin_amdgcn_mfma_f32_16x16x32_bf16(a1[0][kt], bfr, acc0, 0, 0, 0);
            acc1 = __builtin_amdgcn_mfma_f32_16x16x32_bf16(a1[1][kt], bfr, acc1, 0, 0, 0);
        }
        float bb = b1[nt * 16 + c15];
        #pragma unroll
        for (int r = 0; r < 4; r++){
            float x0 = acc0[r] + bb;
            float x1 = acc1[r] + bb;
            Hs[SWZ5(4 * q + r,      nt * 16 + c15)] =
                f2u(0.5f * x0 * (1.f + erff(x0 * 0.70710678118654752f)));
            Hs[SWZ5(16 + 4 * q + r, nt * 16 + c15)] =
                f2u(0.5f * x1 * (1.f + erff(x1 * 0.70710678118654752f)));
        }
    }
    __syncthreads();

    // ---- GEMM2: res += gamma*(H @ W2 + b2), wave covers N-tiles [wv*2, wv*2+2) ----
    f32x4 acc[2][2];
    #pragma unroll
    for (int mt = 0; mt < 2; mt++)
        #pragma unroll
        for (int p = 0; p < 2; p++) acc[mt][p] = (f32x4){0.f,0.f,0.f,0.f};

    #pragma unroll
    for (int kt = 0; kt < 16; kt++){
        s16x8 a0 = *(const s16x8*)(Hs + SWZ5(c15,      kt * 32 + q * 8));
        s16x8 a1v= *(const s16x8*)(Hs + SWZ5(16 + c15, kt * 32 + q * 8));
        #pragma unroll
        for (int p = 0; p < 2; p++){
            int ntp = wv * 2 + p;
            s16x8 bfr = *(const s16x8*)(W2pk + (((ntp << 4) + kt) * 64 + lane) * 8);
            acc[0][p] = __builtin_amdgcn_mfma_f32_16x16x32_bf16(a0,  bfr, acc[0][p], 0, 0, 0);
            acc[1][p] = __builtin_amdgcn_mfma_f32_16x16x32_bf16(a1v, bfr, acc[1][p], 0, 0, 0);
        }
    }
    #pragma unroll
    for (int mt = 0; mt < 2; mt++)
        #pragma unroll
        for (int p = 0; p < 2; p++){
            int col = (wv * 2 + p) * 16 + c15;
            float gv = gamma[col], bv = b2[col];
            #pragma unroll
            for (int r = 0; r < 4; r++){
                int row = m0b + mt * 16 + 4 * q + r;
                float* pr = row_addr(ct_res, x_res, row, split) + col;
                *pr = *pr + gv * (acc[mt][p][r] + bv);
            }
        }
}

// ---------------- final x: out_x += gamma1 * upsampled carrier (in place) ----------------
__global__ void final_x_kernel(float* out_x, const float* __restrict__ out_ct,
                               const float* __restrict__ g1)
{
    int idx = blockIdx.x * 256 + threadIdx.x;   // over 4096*49*128
    int w   = idx / (49 * 128);
    int rem = idx % (49 * 128);
    int p   = rem >> 7;
    int c   = rem & 127;
    int a = p / 7, bc = p % 7;
    int s = ((a * 4) / 7) * 4 + (bc * 4) / 7;
    out_x[idx] = out_x[idx] + g1[c] * out_ct[((size_t)w * 16 + s) * 128 + c];
}

extern "C" void kernel_launch(void* const* d_in, const int* in_sizes, int n_in,
                              void* d_out, int out_size, void* d_ws, size_t ws_size,
                              hipStream_t stream)
{
    const float* x_in        = (const float*)d_in[0];
    const float* ct_in       = (const float*)d_in[1];
    const float* pe_w1       = (const float*)d_in[2];
    const float* pe_b1       = (const float*)d_in[3];
    const float* pe_w2       = (const float*)d_in[4];
    const float* hpe_w1      = (const float*)d_in[5];
    const float* hpe_b1      = (const float*)d_in[6];
    const float* hpe_w2      = (const float*)d_in[7];
    const float* n1_g        = (const float*)d_in[8];
    const float* n1_b        = (const float*)d_in[9];
    const float* n2_g        = (const float*)d_in[10];
    const float* n2_b        = (const float*)d_in[11];
    const float* hn1_g       = (const float*)d_in[12];
    const float* hn1_b       = (const float*)d_in[13];
    const float* hn2_g       = (const float*)d_in[14];
    const float* hn2_b       = (const float*)d_in[15];
    const float* attn_qkv_w  = (const float*)d_in[16];
    const float* attn_proj_w = (const float*)d_in[17];
    const float* attn_proj_b = (const float*)d_in[18];
    const float* attn_cpb_w1 = (const float*)d_in[19];
    const float* attn_cpb_b1 = (const float*)d_in[20];
    const float* attn_cpb_w2 = (const float*)d_in[21];
    const float* hat_qkv_w   = (const float*)d_in[22];
    const float* hat_proj_w  = (const float*)d_in[23];
    const float* hat_proj_b  = (const float*)d_in[24];
    const float* hat_cpb_w1  = (const float*)d_in[25];
    const float* hat_cpb_b1  = (const float*)d_in[26];
    const float* hat_cpb_w2  = (const float*)d_in[27];
    const float* mlp_w1      = (const float*)d_in[28];
    const float* mlp_b1      = (const float*)d_in[29];
    const float* mlp_w2      = (const float*)d_in[30];
    const float* mlp_b2      = (const float*)d_in[31];
    const float* hmlp_w1     = (const float*)d_in[32];
    const float* hmlp_b1     = (const float*)d_in[33];
    const float* hmlp_w2     = (const float*)d_in[34];
    const float* hmlp_b2     = (const float*)d_in[35];
    const float* gamma1      = (const float*)d_in[36];
    const float* gamma2      = (const float*)d_in[37];
    const float* gamma3      = (const float*)d_in[38];
    const float* gamma4      = (const float*)d_in[39];

    const int MC = 256 * 256;   // 65536 carrier tokens
    const int M2 = 4096 * 65;   // 266240 concat tokens

    // residuals live in d_out (float). The out_x region (102.8MB) is dead until
    // win_attn2 writes it; during the carrier phase it holds bf16 qkv (50.3MB)
    // + hat-path packed weights (~0.4MB).
    float* out_x  = (float*)d_out;                        // [4096*49][128]
    float* out_ct = out_x + (size_t)4096 * 49 * 128;      // [65536][128] carrier residual

    ushort* qkvB    = (ushort*)out_x;                     // [65536][384] bf16
    ushort* Whq_pk  = qkvB   + (size_t)MC * 384;          // 24*4*64*8 = 49152
    ushort* Whp_pk  = Whq_pk + 24 * 4 * 64 * 8;           //  8*4*64*8 = 16384
    ushort* W1c_pk  = Whp_pk +  8 * 4 * 64 * 8;           // 32*4*64*8 = 65536
    ushort* W2c_pk  = W1c_pk + 32 * 4 * 64 * 8;           // 8*16*64*8 = 65536

    // workspace: S (33.6MB timeshared) + small tables — identical footprint to
    // all previously-passing rounds (~34 MB). No ws_size-dependent paths.
    char* p = (char*)d_ws;
    float* S     = (float*)p; p += (size_t)MC * 128 * 4;  // carrier attn-out, then main packs + qkv chunk
    float* pe    = (float*)p; p += 49 * 128 * 4;
    float* hpe   = (float*)p; p += 256 * 128 * 4;
    float* btbl7 = (float*)p; p += 169 * 4 * 4;
    float* btbl16= (float*)p; p += 961 * 4 * 4;

    // main-path packed weights — carved from S (dead after carrier proj)
    ushort* Wqkv_pk = (ushort*)S;                 // 24*4*64*8 = 49152 (98304 B)
    ushort* Wp_pk   = Wqkv_pk + 24 * 4 * 64 * 8;  //  8*4*64*8 = 16384 (32768 B)
    ushort* W1m_pk  = Wp_pk   +  8 * 4 * 64 * 8;  // 65536 (131072 B)
    ushort* W2m_pk  = W1m_pk  + 32 * 4 * 64 * 8;  // 65536 (131072 B)
    // chunked main-path qkv scratch: 512 windows * 65 * 384 bf16 = 25.56 MB,
    // at S + 384 KB; 384KB + 25.56MB < 33.55MB S region. Always chunked.
    const int NW = 512;
    ushort* qkvS = (ushort*)((char*)S + 393216);

    posemb_kernel<<<49, 128, 0, stream>>>(pe_w1, pe_b1, pe_w2, pe, 7);
    posemb_kernel<<<256, 128, 0, stream>>>(hpe_w1, hpe_b1, hpe_w2, hpe, 16);
    cpb_kernel<<<3, 64, 0, stream>>>(attn_cpb_w1, attn_cpb_b1, attn_cpb_w2, btbl7, 7);
    cpb_kernel<<<16, 64, 0, stream>>>(hat_cpb_w1, hat_cpb_b1, hat_cpb_w2, btbl16, 16);

    // ---- pack hat-path weights into out_x region (dead until win_attn2) ----
    pack_w_kernel<<<192, 256, 0, stream>>>(hat_qkv_w, Whq_pk, 384, 4);
    pack_w_kernel<<<64, 256, 0, stream>>>(hat_proj_w, Whp_pk, 128, 4);
    pack_w_kernel<<<256, 256, 0, stream>>>(hmlp_w1, W1c_pk, 512, 4);
    pack_w_kernel<<<256, 256, 0, stream>>>(hmlp_w2, W2c_pk, 128, 16);

    // ---- carrier path (residual = out_ct), fully MFMA ----
    ct_init_kernel<<<(MC * 128) / 256, 256, 0, stream>>>(ct_in, hpe, out_ct);
    qkv_mfma<<<MC / 32, 256, 0, stream>>>(out_ct, hn1_g, hn1_b, Whq_pk, qkvB);
    carrier_attn_mfma<<<256 * 4, 256, 0, stream>>>(qkvB, btbl16, S);
    res_gemm_mfma<<<MC / 32, 256, 0, stream>>>(S, out_ct, nullptr, 0,
                                               Whp_pk, hat_proj_b, gamma1);
    mlp_mfma<<<MC / 32, 256, 0, stream>>>(out_ct, nullptr, 0, hn2_g, hn2_b,
                                          W1c_pk, hmlp_b1, W2c_pk, hmlp_b2, gamma2);

    // ---- pack main-path weights into S (dead now) ----
    pack_w_kernel<<<192, 256, 0, stream>>>(attn_qkv_w, Wqkv_pk, 384, 4);
    pack_w_kernel<<<64, 256, 0, stream>>>(attn_proj_w, Wp_pk, 128, 4);
    pack_w_kernel<<<256, 256, 0, stream>>>(mlp_w1, W1m_pk, 512, 4);
    pack_w_kernel<<<256, 256, 0, stream>>>(mlp_w2, W2m_pk, 128, 16);

    // ---- main path: chunked LN+QKV GEMM, then lean per-window attention ----
    for (int c = 0; c < 4096 / NW; c++){
        int w0 = c * NW;
        qkv_split_mfma<<<NW * 65 / 32, 256, 0, stream>>>(out_ct, x_in, pe, w0 * 65,
                                                         n1_g, n1_b, Wqkv_pk, qkvS);
        win_attn2<<<NW, 320, 0, stream>>>(out_ct, out_x, x_in, pe, w0, qkvS,
                                          btbl7, Wp_pk, attn_proj_b, gamma3);
    }

    mlp_mfma<<<M2 / 32, 256, 0, stream>>>(out_ct, out_x, 1, n2_g, n2_b,
                                          W1m_pk, mlp_b1, W2m_pk, mlp_b2, gamma4);

    // ---- finalize (out_ct already holds final carrier residual) ----
    final_x_kernel<<<(4096 * 49 * 128) / 256, 256, 0, stream>>>(out_x, out_ct, gamma1);
}